// Round 1
// baseline (36.337 us; speedup 1.0000x reference)
//
#include <hip/hip_runtime.h>
#include <climits>

// Problem shape: B=256 rows, N=65536 cols, half=32768.
constexpr int HALF = 32768;
constexpr int NV = HALF / 4;       // float4s per half-row
constexpr int NTHREADS = 1024;
constexpr float THRESH = 0.01f;

__global__ __launch_bounds__(NTHREADS)
void loss_rows_kernel(const float* __restrict__ pred,
                      const float* __restrict__ label,
                      float* __restrict__ partial)
{
    const int row = blockIdx.x;
    const int tid = threadIdx.x;
    const size_t rowoff = (size_t)row * (size_t)(2 * HALF);

    const float4* lr4 = (const float4*)(label + rowoff);
    const float4* li4 = (const float4*)(label + rowoff + HALF);
    const float4* pr4 = (const float4*)(pred + rowoff);
    const float4* pi4 = (const float4*)(pred + rowoff + HALF);

    // ---- Phase A: first/last significant index for real and imag halves ----
    int minr = INT_MAX, maxr = -1, mini = INT_MAX, maxi = -1;
    for (int v = tid; v < NV; v += NTHREADS) {
        float4 a = lr4[v];
        float4 b = li4[v];
        int base = v * 4;
        if (fabsf(a.x) > THRESH) { minr = min(minr, base + 0); maxr = max(maxr, base + 0); }
        if (fabsf(a.y) > THRESH) { minr = min(minr, base + 1); maxr = max(maxr, base + 1); }
        if (fabsf(a.z) > THRESH) { minr = min(minr, base + 2); maxr = max(maxr, base + 2); }
        if (fabsf(a.w) > THRESH) { minr = min(minr, base + 3); maxr = max(maxr, base + 3); }
        if (fabsf(b.x) > THRESH) { mini = min(mini, base + 0); maxi = max(maxi, base + 0); }
        if (fabsf(b.y) > THRESH) { mini = min(mini, base + 1); maxi = max(maxi, base + 1); }
        if (fabsf(b.z) > THRESH) { mini = min(mini, base + 2); maxi = max(maxi, base + 2); }
        if (fabsf(b.w) > THRESH) { mini = min(mini, base + 3); maxi = max(maxi, base + 3); }
    }

    // wave (64-lane) reduce
    #pragma unroll
    for (int off = 32; off > 0; off >>= 1) {
        minr = min(minr, __shfl_down(minr, off));
        maxr = max(maxr, __shfl_down(maxr, off));
        mini = min(mini, __shfl_down(mini, off));
        maxi = max(maxi, __shfl_down(maxi, off));
    }

    __shared__ int s_minr[16], s_maxr[16], s_mini[16], s_maxi[16];
    __shared__ int s_fr, s_lr, s_fi, s_li;
    const int wave = tid >> 6;
    const int lane = tid & 63;
    if (lane == 0) {
        s_minr[wave] = minr; s_maxr[wave] = maxr;
        s_mini[wave] = mini; s_maxi[wave] = maxi;
    }
    __syncthreads();
    if (tid == 0) {
        int mr = INT_MAX, Mr = -1, mi = INT_MAX, Mi = -1;
        #pragma unroll
        for (int w = 0; w < NTHREADS / 64; ++w) {
            mr = min(mr, s_minr[w]); Mr = max(Mr, s_maxr[w]);
            mi = min(mi, s_mini[w]); Mi = max(Mi, s_maxi[w]);
        }
        if (Mr < 0) { mr = 0; Mr = HALF - 1; }   // no significant element
        if (Mi < 0) { mi = 0; Mi = HALF - 1; }
        s_fr = mr; s_lr = Mr; s_fi = mi; s_li = Mi;
    }
    __syncthreads();
    const int fr = s_fr, lastr = s_lr, fi = s_fi, lasti = s_li;

    // ---- Phase B: weighted MSE accumulation ----
    float acc = 0.0f;
    for (int v = tid; v < NV; v += NTHREADS) {
        float4 a = lr4[v];
        float4 b = li4[v];
        float4 p = pr4[v];
        float4 q = pi4[v];
        int base = v * 4;

#define COMP(aj, bj, pj, qj, idx)                                   \
        {                                                           \
            float dr  = (pj) - (aj);                                \
            float di  = (qj) - (bj);                                \
            float lint = (aj) * (aj) + (bj) * (bj);                 \
            float pint = (pj) * (pj) + (qj) * (qj);                 \
            float dint = pint - lint;                               \
            float wr = ((idx) < fr || (idx) > lastr) ? 2.0f : 1.0f; \
            float wi = ((idx) < fi || (idx) > lasti) ? 2.0f : 1.0f; \
            acc += wr * dr * dr + wi * di * di + 50.0f * dint * dint; \
        }

        COMP(a.x, b.x, p.x, q.x, base + 0)
        COMP(a.y, b.y, p.y, q.y, base + 1)
        COMP(a.z, b.z, p.z, q.z, base + 2)
        COMP(a.w, b.w, p.w, q.w, base + 3)
#undef COMP
    }

    // block reduce acc
    #pragma unroll
    for (int off = 32; off > 0; off >>= 1)
        acc += __shfl_down(acc, off);

    __shared__ float s_acc[16];
    if (lane == 0) s_acc[wave] = acc;
    __syncthreads();
    if (tid == 0) {
        float t = 0.0f;
        #pragma unroll
        for (int w = 0; w < NTHREADS / 64; ++w) t += s_acc[w];
        partial[row] = t;
    }
}

__global__ void finalize_kernel(const float* __restrict__ partial,
                                float* __restrict__ out, int rows)
{
    const int tid = threadIdx.x;   // 256 threads, 1 block
    float v = 0.0f;
    for (int i = tid; i < rows; i += 256) v += partial[i];
    #pragma unroll
    for (int off = 32; off > 0; off >>= 1)
        v += __shfl_down(v, off);
    __shared__ float s[4];
    if ((tid & 63) == 0) s[tid >> 6] = v;
    __syncthreads();
    if (tid == 0) {
        float t = s[0] + s[1] + s[2] + s[3];
        out[0] = t * (1.0f / ((float)HALF * (float)rows));
    }
}

extern "C" void kernel_launch(void* const* d_in, const int* in_sizes, int n_in,
                              void* d_out, int out_size, void* d_ws, size_t ws_size,
                              hipStream_t stream) {
    const float* pred  = (const float*)d_in[0];
    const float* label = (const float*)d_in[1];
    float* out = (float*)d_out;
    float* partial = (float*)d_ws;

    const int rows = in_sizes[0] / (2 * HALF);   // 256

    loss_rows_kernel<<<rows, NTHREADS, 0, stream>>>(pred, label, partial);
    finalize_kernel<<<1, 256, 0, stream>>>(partial, out, rows);
}

// Round 2
// 34.918 us; speedup vs baseline: 1.0406x; 1.0406x over previous
//
#include <hip/hip_runtime.h>

// B=256 rows, N=65536, half=32768.
constexpr int HALF  = 32768;
constexpr int NSEG  = 8;                 // segments per row
constexpr int SEG   = HALF / NSEG;       // 4096 elements per segment
constexpr int TPB   = 256;
constexpr int NPASS = SEG / 4 / TPB;     // 4 passes of 1 float4/thread/stream
constexpr float THRESH = 0.01f;

// Monoid per half-row stream: (sum of d^2, sum before first significant,
// sum after last significant, any-significant). Invariant: has==0 => pre==post==sum.

__global__ __launch_bounds__(TPB)
void seg_kernel(const float* __restrict__ pred, const float* __restrict__ label,
                float* __restrict__ ws)
{
    const int seg = blockIdx.x;
    const int row = blockIdx.y;
    const int t    = threadIdx.x;
    const int wave = t >> 6, lane = t & 63;

    const size_t row4 = (size_t)row * (size_t)(2 * HALF / 4);
    const float4* lr4 = (const float4*)label + row4 + (size_t)seg * (SEG / 4);
    const float4* li4 = lr4 + (HALF / 4);
    const float4* pr4 = (const float4*)pred + row4 + (size_t)seg * (SEG / 4);
    const float4* pi4 = pr4 + (HALF / 4);

    __shared__ float s_m[NPASS][4][9];

    #pragma unroll
    for (int p = 0; p < NPASS; ++p) {
        const int g = p * TPB + t;               // coalesced: lane t -> granule t
        float4 a = lr4[g], b = li4[g], pp = pr4[g], q = pi4[g];

        // per-thread leaf over 4 ordered elements
        float rs = 0.f, rp = 0.f, rq = 0.f; int rh = 0;
        float is = 0.f, ip = 0.f, iq = 0.f; int ih = 0;
        float ds = 0.f;
#define STEP(ax, bx, px, qx)                                          \
        {                                                             \
            float dr = (px) - (ax), di = (qx) - (bx);                 \
            float cr = dr * dr, ci = di * di;                         \
            float lint = (ax) * (ax) + (bx) * (bx);                   \
            float pint = (px) * (px) + (qx) * (qx);                   \
            float dd = pint - lint; ds += dd * dd;                    \
            rs += cr; is += ci;                                       \
            if (fabsf(ax) > THRESH) { rh = 1; rq = 0.f; }             \
            else { rq += cr; if (!rh) rp += cr; }                     \
            if (fabsf(bx) > THRESH) { ih = 1; iq = 0.f; }             \
            else { iq += ci; if (!ih) ip += ci; }                     \
        }
        STEP(a.x, b.x, pp.x, q.x) STEP(a.y, b.y, pp.y, q.y)
        STEP(a.z, b.z, pp.z, q.z) STEP(a.w, b.w, pp.w, q.w)
#undef STEP

        // ordered wave reduction: ascending offsets merge ADJACENT segments,
        // so the ordered monoid combine stays valid along lane 0's fold path.
        #pragma unroll
        for (int off = 1; off < 64; off <<= 1) {
            float Rrs = __shfl_down(rs, off), Rrp = __shfl_down(rp, off), Rrq = __shfl_down(rq, off);
            int   Rrh = __shfl_down(rh, off);
            float Ris = __shfl_down(is, off), Rip = __shfl_down(ip, off), Riq = __shfl_down(iq, off);
            int   Rih = __shfl_down(ih, off);
            float Rds = __shfl_down(ds, off);
            rp = rh ? rp : (rs + Rrp);
            rq = Rrh ? Rrq : (rq + Rrs);
            rs += Rrs; rh |= Rrh;
            ip = ih ? ip : (is + Rip);
            iq = Rih ? Riq : (iq + Ris);
            is += Ris; ih |= Rih;
            ds += Rds;
        }
        if (lane == 0) {
            float* d = s_m[p][wave];
            d[0] = rs; d[1] = rp; d[2] = rq; d[3] = (float)rh;
            d[4] = is; d[5] = ip; d[6] = iq; d[7] = (float)ih;
            d[8] = ds;
        }
    }
    __syncthreads();

    if (t == 0) {
        // combine the 16 (pass, wave) monoids in segment order
        float rs = 0.f, rp = 0.f, rq = 0.f, rh = 0.f;
        float is = 0.f, ip = 0.f, iq = 0.f, ih = 0.f;
        float ds = 0.f;
        for (int p = 0; p < NPASS; ++p)
            for (int w = 0; w < 4; ++w) {
                const float* d = s_m[p][w];
                float Rrs = d[0], Rrp = d[1], Rrq = d[2], Rrh = d[3];
                float Ris = d[4], Rip = d[5], Riq = d[6], Rih = d[7];
                rp = (rh != 0.f) ? rp : (rs + Rrp);
                rq = (Rrh != 0.f) ? Rrq : (rq + Rrs);
                rs += Rrs; rh += Rrh;
                ip = (ih != 0.f) ? ip : (is + Rip);
                iq = (Rih != 0.f) ? Riq : (iq + Ris);
                is += Ris; ih += Rih;
                ds += d[8];
            }
        float4* o4 = (float4*)(ws + ((size_t)row * NSEG + seg) * 12);
        o4[0] = make_float4(rs, rp, rq, rh);
        o4[1] = make_float4(is, ip, iq, ih);
        o4[2] = make_float4(ds, 0.f, 0.f, 0.f);
    }
}

__global__ void finalize_kernel(const float* __restrict__ ws,
                                float* __restrict__ out, int rows)
{
    const int t = threadIdx.x;   // 256 threads, 1 block
    float total = 0.f;
    for (int r = t; r < rows; r += 256) {
        float rs = 0.f, rp = 0.f, rq = 0.f, rh = 0.f;
        float is = 0.f, ip = 0.f, iq = 0.f, ih = 0.f;
        float ds = 0.f;
        const float4* o4 = (const float4*)(ws + (size_t)r * NSEG * 12);
        for (int s = 0; s < NSEG; ++s) {
            float4 A = o4[s * 3 + 0], B = o4[s * 3 + 1], C = o4[s * 3 + 2];
            rp = (rh != 0.f) ? rp : (rs + A.y);
            rq = (A.w != 0.f) ? A.z : (rq + A.x);
            rs += A.x; rh += A.w;
            ip = (ih != 0.f) ? ip : (is + B.y);
            iq = (B.w != 0.f) ? B.z : (iq + B.x);
            is += B.x; ih += B.w;
            ds += C.x;
        }
        float extra_r = (rh != 0.f) ? (rp + rq) : 0.f;
        float extra_i = (ih != 0.f) ? (ip + iq) : 0.f;
        total += rs + is + 50.f * ds + extra_r + extra_i;
    }
    #pragma unroll
    for (int off = 32; off > 0; off >>= 1) total += __shfl_down(total, off);
    __shared__ float s[4];
    if ((t & 63) == 0) s[t >> 6] = total;
    __syncthreads();
    if (t == 0) out[0] = (s[0] + s[1] + s[2] + s[3]) * (1.0f / ((float)HALF * (float)rows));
}

extern "C" void kernel_launch(void* const* d_in, const int* in_sizes, int n_in,
                              void* d_out, int out_size, void* d_ws, size_t ws_size,
                              hipStream_t stream) {
    const float* pred  = (const float*)d_in[0];
    const float* label = (const float*)d_in[1];
    float* out = (float*)d_out;
    float* ws  = (float*)d_ws;

    const int rows = in_sizes[0] / (2 * HALF);   // 256

    dim3 grid(NSEG, rows);
    seg_kernel<<<grid, TPB, 0, stream>>>(pred, label, ws);
    finalize_kernel<<<1, 256, 0, stream>>>(ws, out, rows);
}

// Round 3
// 31.518 us; speedup vs baseline: 1.1529x; 1.1079x over previous
//
#include <hip/hip_runtime.h>

// B=256 rows, N=65536, half=32768.
constexpr int HALF = 32768;
constexpr int TPB  = 256;
constexpr int CPT  = 16;               // contiguous elements per thread
constexpr int SEG  = TPB * CPT;        // 4096 elements per block-segment
constexpr int NSEG = HALF / SEG;       // 8 segments per row
constexpr float THRESH = 0.01f;

// Ordered monoid per stream: (sum d^2, sum-before-first-significant,
// sum-after-last-significant, has-significant).
// Combine(L,R): pre = L.has ? L.pre : L.sum + R.pre
//               post = R.has ? R.post : L.post + R.sum
//               sum = L.sum + R.sum ; has = L.has | R.has

__global__ __launch_bounds__(TPB)
void seg_kernel(const float* __restrict__ pred, const float* __restrict__ label,
                float* __restrict__ ws)
{
    const int seg = blockIdx.x;
    const int row = blockIdx.y;
    const int t    = threadIdx.x;
    const int wave = t >> 6, lane = t & 63;

    // thread t owns elements [seg*SEG + t*16, +16) of each half-row stream
    const size_t base4 = (size_t)row * (size_t)(2 * HALF / 4)
                       + (size_t)seg * (SEG / 4) + (size_t)t * 4;
    const float4* lr4 = (const float4*)label + base4;
    const float4* li4 = lr4 + (HALF / 4);
    const float4* pr4 = (const float4*)pred + base4;
    const float4* pi4 = pr4 + (HALF / 4);

    // issue ALL loads upfront — 16 independent 16B loads per thread
    float4 A[4], Bv[4], P[4], Q[4];
    #pragma unroll
    for (int j = 0; j < 4; ++j) { A[j] = lr4[j]; }
    #pragma unroll
    for (int j = 0; j < 4; ++j) { Bv[j] = li4[j]; }
    #pragma unroll
    for (int j = 0; j < 4; ++j) { P[j] = pr4[j]; }
    #pragma unroll
    for (int j = 0; j < 4; ++j) { Q[j] = pi4[j]; }

    // per-thread ordered fold over 16 elements (pure VALU, branchless)
    float rs = 0.f, rp = 0.f, rq = 0.f; int rh = 0;
    float is = 0.f, ip = 0.f, iq = 0.f; int ih = 0;
    float ds = 0.f;

#define STEP(ax, bx, px, qx)                                   \
    {                                                          \
        float dr = (px) - (ax), di = (qx) - (bx);              \
        float cr = dr * dr, ci = di * di;                      \
        float lint = (ax) * (ax) + (bx) * (bx);                \
        float pint = (px) * (px) + (qx) * (qx);                \
        float dd = pint - lint; ds += dd * dd;                 \
        rs += cr; is += ci;                                    \
        bool sr = fabsf(ax) > THRESH;                          \
        bool si = fabsf(bx) > THRESH;                          \
        rq = sr ? 0.f : (rq + cr);                             \
        rp = (sr || rh) ? rp : (rp + cr);                      \
        rh |= (int)sr;                                         \
        iq = si ? 0.f : (iq + ci);                             \
        ip = (si || ih) ? ip : (ip + ci);                      \
        ih |= (int)si;                                         \
    }

    #pragma unroll
    for (int j = 0; j < 4; ++j) {
        STEP(A[j].x, Bv[j].x, P[j].x, Q[j].x)
        STEP(A[j].y, Bv[j].y, P[j].y, Q[j].y)
        STEP(A[j].z, Bv[j].z, P[j].z, Q[j].z)
        STEP(A[j].w, Bv[j].w, P[j].w, Q[j].w)
    }
#undef STEP

    // ONE ordered wave reduce (ascending offsets merge adjacent lane ranges;
    // lane 0's fold path only combines contiguous, in-order ranges).
    #pragma unroll
    for (int off = 1; off < 64; off <<= 1) {
        float Rrs = __shfl_down(rs, off), Rrp = __shfl_down(rp, off), Rrq = __shfl_down(rq, off);
        int   Rrh = __shfl_down(rh, off);
        float Ris = __shfl_down(is, off), Rip = __shfl_down(ip, off), Riq = __shfl_down(iq, off);
        int   Rih = __shfl_down(ih, off);
        float Rds = __shfl_down(ds, off);
        rp = rh ? rp : (rs + Rrp);
        rq = Rrh ? Rrq : (rq + Rrs);
        rs += Rrs; rh |= Rrh;
        ip = ih ? ip : (is + Rip);
        iq = Rih ? Riq : (iq + Ris);
        is += Ris; ih |= Rih;
        ds += Rds;
    }

    __shared__ float s_m[4][9];
    if (lane == 0) {
        float* d = s_m[wave];
        d[0] = rs; d[1] = rp; d[2] = rq; d[3] = (float)rh;
        d[4] = is; d[5] = ip; d[6] = iq; d[7] = (float)ih;
        d[8] = ds;
    }
    __syncthreads();

    if (t == 0) {
        float ars = 0.f, arp = 0.f, arq = 0.f, arh = 0.f;
        float ais = 0.f, aip = 0.f, aiq = 0.f, aih = 0.f;
        float ads = 0.f;
        #pragma unroll
        for (int w = 0; w < 4; ++w) {
            const float* d = s_m[w];
            arp = (arh != 0.f) ? arp : (ars + d[1]);
            arq = (d[3] != 0.f) ? d[2] : (arq + d[0]);
            ars += d[0]; arh += d[3];
            aip = (aih != 0.f) ? aip : (ais + d[5]);
            aiq = (d[7] != 0.f) ? d[6] : (aiq + d[4]);
            ais += d[4]; aih += d[7];
            ads += d[8];
        }
        float4* o4 = (float4*)(ws + ((size_t)row * NSEG + seg) * 12);
        o4[0] = make_float4(ars, arp, arq, arh);
        o4[1] = make_float4(ais, aip, aiq, aih);
        o4[2] = make_float4(ads, 0.f, 0.f, 0.f);
    }
}

__global__ void finalize_kernel(const float* __restrict__ ws,
                                float* __restrict__ out, int rows)
{
    const int t = threadIdx.x;   // 256 threads, 1 block
    float total = 0.f;
    for (int r = t; r < rows; r += 256) {
        float rs = 0.f, rp = 0.f, rq = 0.f, rh = 0.f;
        float is = 0.f, ip = 0.f, iq = 0.f, ih = 0.f;
        float ds = 0.f;
        const float4* o4 = (const float4*)(ws + (size_t)r * NSEG * 12);
        for (int s = 0; s < NSEG; ++s) {
            float4 A = o4[s * 3 + 0], B = o4[s * 3 + 1], C = o4[s * 3 + 2];
            rp = (rh != 0.f) ? rp : (rs + A.y);
            rq = (A.w != 0.f) ? A.z : (rq + A.x);
            rs += A.x; rh += A.w;
            ip = (ih != 0.f) ? ip : (is + B.y);
            iq = (B.w != 0.f) ? B.z : (iq + B.x);
            is += B.x; ih += B.w;
            ds += C.x;
        }
        float extra_r = (rh != 0.f) ? (rp + rq) : 0.f;
        float extra_i = (ih != 0.f) ? (ip + iq) : 0.f;
        total += rs + is + 50.f * ds + extra_r + extra_i;
    }
    #pragma unroll
    for (int off = 32; off > 0; off >>= 1) total += __shfl_down(total, off);
    __shared__ float s[4];
    if ((t & 63) == 0) s[t >> 6] = total;
    __syncthreads();
    if (t == 0) out[0] = (s[0] + s[1] + s[2] + s[3]) * (1.0f / ((float)HALF * (float)rows));
}

extern "C" void kernel_launch(void* const* d_in, const int* in_sizes, int n_in,
                              void* d_out, int out_size, void* d_ws, size_t ws_size,
                              hipStream_t stream) {
    const float* pred  = (const float*)d_in[0];
    const float* label = (const float*)d_in[1];
    float* out = (float*)d_out;
    float* ws  = (float*)d_ws;

    const int rows = in_sizes[0] / (2 * HALF);   // 256

    dim3 grid(NSEG, rows);
    seg_kernel<<<grid, TPB, 0, stream>>>(pred, label, ws);
    finalize_kernel<<<1, 256, 0, stream>>>(ws, out, rows);
}

// Round 4
// 28.690 us; speedup vs baseline: 1.2665x; 1.0986x over previous
//
#include <hip/hip_runtime.h>
#include <climits>

// B=256 rows, N=65536, half=32768.
constexpr int HALF = 32768;
constexpr int TPB  = 256;
constexpr int SEG  = 4096;             // elements per (row,seg) per half-stream
constexpr int NSEG = HALF / SEG;       // 8
constexpr int NPASS = SEG / 4 / TPB;   // 4 coalesced float4 passes
constexpr float THRESH = 0.01f;

// ---------------- Kernel A: coalesced streaming pass ----------------
// Per (row,seg): partial unweighted sum (dr^2 + di^2 + 50*dint^2) and
// min/max significant element index for real & imag label halves.
__global__ __launch_bounds__(TPB)
void main_kernel(const float* __restrict__ pred, const float* __restrict__ label,
                 float* __restrict__ part_sum, int4* __restrict__ part_idx)
{
    const int seg = blockIdx.x, row = blockIdx.y;
    const int t = threadIdx.x, wave = t >> 6, lane = t & 63;

    const size_t rb4 = (size_t)row * (size_t)(2 * HALF / 4);
    const int sb4 = seg * (SEG / 4);
    const float4* lr4 = (const float4*)label + rb4 + sb4;
    const float4* li4 = lr4 + (HALF / 4);
    const float4* pr4 = (const float4*)pred + rb4 + sb4;
    const float4* pi4 = pr4 + (HALF / 4);

    float sum = 0.f;
    int minr = INT_MAX, maxr = -1, mini = INT_MAX, maxi = -1;

    #pragma unroll
    for (int p = 0; p < NPASS; ++p) {
        const int v = p * TPB + t;            // lane l -> float4 l : coalesced
        float4 a = lr4[v], b = li4[v], pp = pr4[v], q = pi4[v];
        const int base = seg * SEG + v * 4;   // global element index in half-row

#define STEP(ax, bx, px, qx, idx)                              \
        {                                                      \
            float dr = (px) - (ax), di = (qx) - (bx);          \
            float lint = (ax) * (ax) + (bx) * (bx);            \
            float pint = (px) * (px) + (qx) * (qx);            \
            float dd = pint - lint;                            \
            sum += dr * dr + di * di + 50.f * dd * dd;         \
            if (fabsf(ax) > THRESH) {                          \
                minr = min(minr, (idx)); maxr = max(maxr, (idx)); \
            }                                                  \
            if (fabsf(bx) > THRESH) {                          \
                mini = min(mini, (idx)); maxi = max(maxi, (idx)); \
            }                                                  \
        }
        STEP(a.x, b.x, pp.x, q.x, base + 0)
        STEP(a.y, b.y, pp.y, q.y, base + 1)
        STEP(a.z, b.z, pp.z, q.z, base + 2)
        STEP(a.w, b.w, pp.w, q.w, base + 3)
#undef STEP
    }

    // unordered wave reduce (sum / min / max)
    #pragma unroll
    for (int off = 32; off > 0; off >>= 1) {
        sum  += __shfl_down(sum, off);
        minr  = min(minr, __shfl_down(minr, off));
        maxr  = max(maxr, __shfl_down(maxr, off));
        mini  = min(mini, __shfl_down(mini, off));
        maxi  = max(maxi, __shfl_down(maxi, off));
    }

    __shared__ float s_sum[4];
    __shared__ int s_idx[4][4];
    if (lane == 0) {
        s_sum[wave] = sum;
        s_idx[wave][0] = minr; s_idx[wave][1] = maxr;
        s_idx[wave][2] = mini; s_idx[wave][3] = maxi;
    }
    __syncthreads();
    if (t == 0) {
        float S = 0.f; int mr = INT_MAX, Mr = -1, mi = INT_MAX, Mi = -1;
        #pragma unroll
        for (int w = 0; w < 4; ++w) {
            S += s_sum[w];
            mr = min(mr, s_idx[w][0]); Mr = max(Mr, s_idx[w][1]);
            mi = min(mi, s_idx[w][2]); Mi = max(Mi, s_idx[w][3]);
        }
        const int slot = row * NSEG + seg;
        part_sum[slot] = S;
        part_idx[slot] = make_int4(mr, Mr, mi, Mi);
    }
}

// ---------------- Kernel B: per-row edges + total ----------------
__global__ __launch_bounds__(TPB)
void edge_kernel(const float* __restrict__ pred, const float* __restrict__ label,
                 const float* __restrict__ part_sum, const int4* __restrict__ part_idx,
                 float* __restrict__ row_tot)
{
    const int row = blockIdx.x;
    const int t = threadIdx.x, wave = t >> 6, lane = t & 63;

    float base = 0.f;
    int fr = INT_MAX, lastr = -1, fi = INT_MAX, lasti = -1;
    #pragma unroll
    for (int s = 0; s < NSEG; ++s) {
        base += part_sum[row * NSEG + s];
        int4 v = part_idx[row * NSEG + s];
        fr = min(fr, v.x); lastr = max(lastr, v.y);
        fi = min(fi, v.z); lasti = max(lasti, v.w);
    }
    if (lastr < 0) { fr = 0; lastr = HALF - 1; }
    if (lasti < 0) { fi = 0; lasti = HALF - 1; }

    const float* Lr = label + (size_t)row * (2 * HALF);
    const float* Li = Lr + HALF;
    const float* Pr = pred + (size_t)row * (2 * HALF);
    const float* Pi = Pr + HALF;

    // extra +1*d^2 outside [first,last] (typically ~0-2 elements per edge)
    float ex = 0.f;
    for (int i = t; i < fr; i += TPB)             { float d = Pr[i] - Lr[i]; ex += d * d; }
    for (int i = lastr + 1 + t; i < HALF; i += TPB) { float d = Pr[i] - Lr[i]; ex += d * d; }
    for (int i = t; i < fi; i += TPB)             { float d = Pi[i] - Li[i]; ex += d * d; }
    for (int i = lasti + 1 + t; i < HALF; i += TPB) { float d = Pi[i] - Li[i]; ex += d * d; }

    #pragma unroll
    for (int off = 32; off > 0; off >>= 1) ex += __shfl_down(ex, off);
    __shared__ float s_ex[4];
    if (lane == 0) s_ex[wave] = ex;
    __syncthreads();
    if (t == 0)
        row_tot[row] = base + s_ex[0] + s_ex[1] + s_ex[2] + s_ex[3];
}

// ---------------- Kernel C: final deterministic reduce ----------------
__global__ void finalize_kernel(const float* __restrict__ row_tot,
                                float* __restrict__ out, int rows)
{
    const int t = threadIdx.x;   // 256 threads, 1 block
    float v = 0.f;
    for (int i = t; i < rows; i += 256) v += row_tot[i];
    #pragma unroll
    for (int off = 32; off > 0; off >>= 1) v += __shfl_down(v, off);
    __shared__ float s[4];
    if ((t & 63) == 0) s[t >> 6] = v;
    __syncthreads();
    if (t == 0)
        out[0] = (s[0] + s[1] + s[2] + s[3]) * (1.0f / ((float)HALF * (float)rows));
}

extern "C" void kernel_launch(void* const* d_in, const int* in_sizes, int n_in,
                              void* d_out, int out_size, void* d_ws, size_t ws_size,
                              hipStream_t stream) {
    const float* pred  = (const float*)d_in[0];
    const float* label = (const float*)d_in[1];
    float* out = (float*)d_out;

    const int rows = in_sizes[0] / (2 * HALF);   // 256
    const int nslots = rows * NSEG;              // 2048

    float* part_sum = (float*)d_ws;                          // 2048 floats
    int4*  part_idx = (int4*)((char*)d_ws + nslots * 4);     // 2048 int4 (16B-aligned: 8192 % 16 == 0)
    float* row_tot  = (float*)((char*)d_ws + nslots * 4 + nslots * 16);  // 256 floats

    dim3 gridA(NSEG, rows);
    main_kernel<<<gridA, TPB, 0, stream>>>(pred, label, part_sum, part_idx);
    edge_kernel<<<rows, TPB, 0, stream>>>(pred, label, part_sum, part_idx, row_tot);
    finalize_kernel<<<1, 256, 0, stream>>>(row_tot, out, rows);
}